// Round 8
// baseline (228.525 us; speedup 1.0000x reference)
//
#include <hip/hip_runtime.h>

// Problem constants
#define N_TOK  16384   // B*S
#define D_IN   1024
#define D_OUT  1024
#define N_CENT 1024

// GEMM tiling (BK=32: R3 measured 59.9us vs 64.6 at BK=64)
#define BM 128
#define BN 128
#define BK 32
#define NTILE (N_CENT / BN)   // 8

// Fused tail: tokens per block. 512 blocks -> 2/CU.
#define TOK_PER_BLK 32
#define TAIL_BLOCKS (N_TOK / TOK_PER_BLK)   // 512

// Margin: bf16 approx error on d2 max ~1.6e-2 over all pairs; TAU >= 2*maxerr
// guarantees (a) unique-gap argmin exact, (b) candidate set {d2a <= gmin+TAU}
// contains the exact argmin. TAU=0.05 validated R3/R4/R5/R7/R8 (absmax 0).
#define TAU 0.05f

#define SENT 0xFFFFFFFFFFFFFFFFull

typedef __attribute__((ext_vector_type(8))) short short8;
typedef __attribute__((ext_vector_type(4))) float float4v;
typedef unsigned int u32;
typedef unsigned short u16;
typedef unsigned long long u64;

__device__ __forceinline__ void async_copy16(const void* g, void* l) {
    __builtin_amdgcn_global_load_lds(
        (const __attribute__((address_space(1))) u32*)g,
        (__attribute__((address_space(3))) u32*)l, 16, 0, 0);
}

__device__ __forceinline__ u16 f32_to_bf16_rne(float f) {
    u32 u = __float_as_uint(f);
    u32 r = (u + 0x7FFFu + ((u >> 16) & 1u)) >> 16;
    return (u16)r;
}

__device__ __forceinline__ u64 umin64(u64 a, u64 b) { return a < b ? a : b; }
__device__ __forceinline__ u64 umax64(u64 a, u64 b) { return a > b ? a : b; }
__device__ __forceinline__ float pk_val(u64 p) { return __uint_as_float((u32)(p >> 32)); }

// Merge two ascending-sorted u64 triples into (s1,s2,s3).
// Packed key (d2_bits<<32)|idx with d2>0: u64 order == lex (val, idx) ==
// numpy first-occurrence argmin tie-break. (R8-validated, absmax 0.)
__device__ __forceinline__ void merge3u(
    u64& s1, u64& s2, u64& s3, u64 b1, u64 b2, u64 b3)
{
    const u64 m1 = umin64(s1, b1);
    const u64 M1 = umax64(s1, b1);
    const u64 m2 = umin64(s2, b2);
    const u64 m3 = umin64(s3, b3);
    s1 = m1;
    const u64 t2 = umin64(M1, m2);
    s3 = umin64(umax64(M1, m2), m3);
    s2 = t2;
}

// Wave dot product, summation order identical to R5/R7/R8-validated rescore.
__device__ __forceinline__ float wave_dot(
    const float* __restrict__ X, const float* __restrict__ C,
    int m, int n, int l)
{
    const float4* xr = (const float4*)(X + (size_t)m * D_IN);
    const float4* cr = (const float4*)(C + (size_t)n * D_IN);
    float p = 0.f;
#pragma unroll
    for (int k = 0; k < 4; ++k) {
        const float4 cv = cr[l + 64 * k];
        const float4 xv = xr[l + 64 * k];
        p = fmaf(xv.x, cv.x, p); p = fmaf(xv.y, cv.y, p);
        p = fmaf(xv.z, cv.z, p); p = fmaf(xv.w, cv.w, p);
    }
#pragma unroll
    for (int off = 32; off > 0; off >>= 1) p += __shfl_xor(p, off);
    return p;
}

__device__ __forceinline__ void gather_write(
    const float* __restrict__ table, const float* __restrict__ bias,
    float* __restrict__ out, int m, int bi, int l)
{
    const float4* tr = (const float4*)(table + (size_t)bi * D_OUT);
    const float4* br = (const float4*)bias;
    float4* orow = (float4*)(out + (size_t)m * D_OUT);
#pragma unroll
    for (int i = 0; i < 4; ++i) {
        const float4 tv = tr[l + i * 64];
        const float4 bv = br[l + i * 64];
        orow[l + i * 64] = make_float4(tv.x + bv.x, tv.y + bv.y,
                                       tv.z + bv.z, tv.w + bv.w);
    }
}

// ---------------------------------------------------------------------------
// Fused fp32->bf16 convert + row norms for X and C + ovf counter zero.
// ---------------------------------------------------------------------------
__global__ __launch_bounds__(256) void prep_kernel(
    const float* __restrict__ X, const float* __restrict__ C,
    u16* __restrict__ Xh, u16* __restrict__ Ch,
    float* __restrict__ xsq, float* __restrict__ csq,
    int* __restrict__ g_ctr)
{
    if (blockIdx.x == 0 && threadIdx.x < 2) g_ctr[threadIdx.x] = 0;

    const int wv = threadIdx.x >> 6;
    const int l  = threadIdx.x & 63;
    int row = blockIdx.x * 4 + wv;
    const float* src; u16* dsth; float* dsts;
    if (row < N_TOK) { src = X; dsth = Xh; dsts = xsq; }
    else { row -= N_TOK; src = C; dsth = Ch; dsts = csq; }
    const float4* xr = (const float4*)(src + (size_t)row * D_IN);
    ushort4* hr = (ushort4*)(dsth + (size_t)row * D_IN);
    float s = 0.f;
#pragma unroll
    for (int i = 0; i < 4; ++i) {
        float4 v = xr[l + i * 64];
        ushort4 o;
        o.x = f32_to_bf16_rne(v.x); o.y = f32_to_bf16_rne(v.y);
        o.z = f32_to_bf16_rne(v.z); o.w = f32_to_bf16_rne(v.w);
        hr[l + i * 64] = o;
        s += v.x * v.x + v.y * v.y + v.z * v.z + v.w * v.w;
    }
#pragma unroll
    for (int off = 32; off > 0; off >>= 1) s += __shfl_down(s, off);
    if (l == 0) dsts[row] = s;
}

// ---------------------------------------------------------------------------
// bf16 MFMA GEMM + fused per-tile top-3 epilogue (u64-packed, R8-proven).
// R8: EXACT revert to the R4 structure (single 16KB buffer, __syncthreads,
// conflict-free (r>>1)&3 swizzle -- proven 70.6us / bank-conflict 0).
// R6 (source dbuf) was null and R7 (inline-asm counted vmcnt) was -70%
// (m141 reproduced: order-pinning defeats compiler scheduling, VGPR 104).
// The 2-phase structure's ~70us is its ceiling; further GEMM gains need the
// full 8-phase 256^2 co-designed template, not incremental grafts.
// Added ybase: the grid is split into two dispatches (n-tiles 0-3, 4-7)
// purely for PROFILER VISIBILITY -- each ~36us, dropping the top-5 cutoff
// so aux kernels >=36us surface in the counter table.
// ---------------------------------------------------------------------------
__global__ __launch_bounds__(256) void gemm_top3_kernel(
    const u16* __restrict__ Xh, const u16* __restrict__ Ch,
    const float* __restrict__ x_sq, const float* __restrict__ c_sq,
    u64* __restrict__ pt1, u64* __restrict__ pt2, u64* __restrict__ pt3,
    int ybase)
{
    __shared__ __align__(16) u16 As[BM * BK];   // 8 KB
    __shared__ __align__(16) u16 Bs[BN * BK];   // 8 KB

    const int t  = threadIdx.x;
    const int w  = t >> 6;
    const int l  = t & 63;
    const int wi = w >> 1, wj = w & 1;
    const int nt = ybase + blockIdx.y;
    const int m0 = blockIdx.x * BM;
    const int n0 = nt * BN;
    const int quad = l >> 4;
    const int r15  = l & 15;

    float4v acc[4][4];
#pragma unroll
    for (int i = 0; i < 4; ++i)
#pragma unroll
        for (int j = 0; j < 4; ++j)
            acc[i][j] = (float4v){0.f, 0.f, 0.f, 0.f};

    for (int k0 = 0; k0 < D_IN; k0 += BK) {
        // 512 16B slots per operand: slot s -> row r=s>>2, lds-octet s&3,
        // global octet (s&3)^((r>>1)&3).  (R4 conflict-free swizzle)
#pragma unroll
        for (int rnd = 0; rnd < 2; ++rnd) {
            const int s = rnd * 256 + t;
            const int r = s >> 2;
            const int q = (s & 3) ^ ((r >> 1) & 3);
            async_copy16(Xh + (size_t)(m0 + r) * D_IN + k0 + q * 8, As + s * 8);
            async_copy16(Ch + (size_t)(n0 + r) * D_IN + k0 + q * 8, Bs + s * 8);
        }
        __syncthreads();

        short8 af[4], bfr[4];
#pragma unroll
        for (int i = 0; i < 4; ++i) {
            const int r = wi * 64 + i * 16 + r15;
            af[i] = *(const short8*)(As + (r * 4 + (quad ^ ((r >> 1) & 3))) * 8);
        }
#pragma unroll
        for (int j = 0; j < 4; ++j) {
            const int r = wj * 64 + j * 16 + r15;
            bfr[j] = *(const short8*)(Bs + (r * 4 + (quad ^ ((r >> 1) & 3))) * 8);
        }
#pragma unroll
        for (int i = 0; i < 4; ++i)
#pragma unroll
            for (int j = 0; j < 4; ++j)
                acc[i][j] = __builtin_amdgcn_mfma_f32_16x16x32_bf16(
                    af[i], bfr[j], acc[i][j], 0, 0, 0);
        __syncthreads();
    }

    // Epilogue: per-64-col-subtile top-3 (u64-packed), cross-wave merge.
    u64* red = (u64*)As;   // [BM][2] triples = 6144 B, reuses staging arena

    const int nbase = n0 + wj * 64 + r15;
    float cq[4];
#pragma unroll
    for (int j = 0; j < 4; ++j) cq[j] = c_sq[nbase + j * 16];

#pragma unroll
    for (int i = 0; i < 4; ++i) {
#pragma unroll
        for (int reg = 0; reg < 4; ++reg) {
            const int rloc = wi * 64 + i * 16 + quad * 4 + reg;
            const float xq = x_sq[m0 + rloc];
            const float d0 = (xq - 2.0f * acc[i][0][reg]) + cq[0];
            u64 s1 = ((u64)__float_as_uint(d0) << 32) | (u32)nbase;
            u64 s2 = SENT, s3 = SENT;
#pragma unroll
            for (int j = 1; j < 4; ++j) {
                const float dj = (xq - 2.0f * acc[i][j][reg]) + cq[j];
                const u64 v = ((u64)__float_as_uint(dj) << 32) | (u32)(nbase + j * 16);
                if (v < s1)      { s3 = s2; s2 = s1; s1 = v; }
                else if (v < s2) { s3 = s2; s2 = v; }
                else if (v < s3) { s3 = v; }
            }
#pragma unroll
            for (int off = 1; off < 16; off <<= 1) {
                const u64 b1 = __shfl_xor(s1, off);
                const u64 b2 = __shfl_xor(s2, off);
                const u64 b3 = __shfl_xor(s3, off);
                merge3u(s1, s2, s3, b1, b2, b3);
            }
            if (r15 == 0) {
                red[(rloc * 2 + wj) * 3 + 0] = s1;
                red[(rloc * 2 + wj) * 3 + 1] = s2;
                red[(rloc * 2 + wj) * 3 + 2] = s3;
            }
        }
    }
    __syncthreads();
    if (t < BM) {
        u64 a1 = red[(t * 2) * 3], a2 = red[(t * 2) * 3 + 1], a3 = red[(t * 2) * 3 + 2];
        merge3u(a1, a2, a3,
                red[(t * 2 + 1) * 3], red[(t * 2 + 1) * 3 + 1], red[(t * 2 + 1) * 3 + 2]);
        const size_t o = (size_t)nt * N_TOK + m0 + t;
        pt1[o] = a1; pt2[o] = a2; pt3[o] = a3;
    }
}

// ---------------------------------------------------------------------------
// Fused tail for the COMMON path: reduce + candidate rescore + gather, all
// block-local (R8 numerics). Rare ovf tokens deferred to the globally-
// parallel ovf kernel (R2 post-mortem: in-block ovf rescore = straggler).
// ---------------------------------------------------------------------------
__global__ __launch_bounds__(256) void tail_kernel(
    const u64* __restrict__ pt1, const u64* __restrict__ pt2,
    const u64* __restrict__ pt3,
    const float* __restrict__ X, const float* __restrict__ C,
    const float* __restrict__ x_sq, const float* __restrict__ c_sq,
    const float* __restrict__ table, const float* __restrict__ bias,
    float* __restrict__ out,
    u64* __restrict__ packed_g, int* __restrict__ ovf_list,
    int* __restrict__ ovf_cnt, int* __restrict__ g_ctr)
{
    __shared__ u32 s_work[TOK_PER_BLK * 2 * NTILE];  // 2KB, exact worst case
    __shared__ u64 s_packed[TOK_PER_BLK];
    __shared__ int s_idx[TOK_PER_BLK];
    __shared__ int s_skip[TOK_PER_BLK];
    __shared__ int s_nw;

    const int tid = threadIdx.x;
    const int m0  = blockIdx.x * TOK_PER_BLK;
    const int wv  = tid >> 6;
    const int l   = tid & 63;

    if (tid == 0) s_nw = 0;
    __syncthreads();

    // ---- Phase 1: per-token merge of NTILE tile top-3 triples (R8 logic) ----
    if (tid < TOK_PER_BLK) {
        const int m = m0 + tid;
        u64 t1[NTILE], t2[NTILE], t3[NTILE];
#pragma unroll
        for (int q = 0; q < NTILE; ++q) {
            t1[q] = pt1[(size_t)q * N_TOK + m];
            t2[q] = pt2[(size_t)q * N_TOK + m];
            t3[q] = pt3[(size_t)q * N_TOK + m];
        }
        u64 g1 = t1[0], g2 = t2[0], g3 = t3[0];
#pragma unroll
        for (int q = 1; q < NTILE; ++q) merge3u(g1, g2, g3, t1[q], t2[q], t3[q]);

        const float thr = pk_val(g1) + TAU;
        s_idx[tid] = (int)(g1 & 1023u);
        s_packed[tid] = SENT;

        bool ovf = false;
#pragma unroll
        for (int q = 0; q < NTILE; ++q)
            if (pk_val(t3[q]) <= thr) ovf = true;

        s_skip[tid] = ovf ? 1 : 0;
        if (ovf) {
            // Defer: full-row exact rescore with GLOBAL parallelism.
            packed_g[m] = SENT;                       // init before append
            ovf_cnt[m]  = 16;                         // 16 chunks pending
            const int pos = atomicAdd(&g_ctr[0], 1);  // device-scope
            ovf_list[pos] = m;
        } else if (pk_val(g2) <= thr) {
            int k = 0; u32 cd[2 * NTILE];
#pragma unroll
            for (int q = 0; q < NTILE; ++q) {
                if (pk_val(t1[q]) <= thr) cd[k++] = (u32)(t1[q] & 1023u);
                if (pk_val(t2[q]) <= thr) cd[k++] = (u32)(t2[q] & 1023u);
            }
            const int base = atomicAdd(&s_nw, k);
            for (int i = 0; i < k; ++i)
                s_work[base + i] = ((u32)tid << 10) | cd[i];
        }
    }
    __syncthreads();

    // ---- Phase 2: exact fp32 candidate rescore (bounded: <=16/token) ----
    {
        const int nw = s_nw;
        for (int i = wv; i < nw; i += 4) {
            const u32 item = s_work[i];
            const int mt = (int)(item >> 10);
            const int n  = (int)(item & 1023u);
            const int m = m0 + mt;
            const float p = wave_dot(X, C, m, n, l);
            if (l == 0) {
                const float d2 = (x_sq[m] - 2.0f * p) + c_sq[n];
                const u64 pk = ((u64)__float_as_uint(d2) << 32) | (u32)n;
                atomicMin(&s_packed[mt], pk);
            }
        }
    }
    __syncthreads();

    // ---- Phase 3: gather + bias for non-deferred tokens ----
    for (int mt = wv; mt < TOK_PER_BLK; mt += 4) {
        if (s_skip[mt]) continue;
        const u64 pk = s_packed[mt];
        const int bi = (pk != SENT) ? (int)(pk & 1023u) : s_idx[mt];
        gather_write(table, bias, out, m0 + mt, bi, l);
    }
}

// ---------------------------------------------------------------------------
// Deferred ovf rescore + fused gather. Chunks of 64 centroids spread over
// the grid (16 chunks/token); exact fp32 wave_dot + global u64 atomicMin
// (R8 numerics). Last-decrementer of the token's chunk counter gathers.
// ---------------------------------------------------------------------------
__global__ __launch_bounds__(256) void ovf_kernel(
    const float* __restrict__ X, const float* __restrict__ C,
    const float* __restrict__ x_sq, const float* __restrict__ c_sq,
    const int* __restrict__ ovf_list, const int* __restrict__ g_ctr,
    u64* __restrict__ packed_g, int* __restrict__ ovf_cnt,
    const float* __restrict__ table, const float* __restrict__ bias,
    float* __restrict__ out)
{
    __shared__ int s_flag;
    const int tid = threadIdx.x;
    const int wv = tid >> 6;
    const int l  = tid & 63;
    const int novf = g_ctr[0];
    const int nchunks = novf << 4;          // 16 x 64-centroid chunks per token
    for (int ch = blockIdx.x; ch < nchunks; ch += gridDim.x) {
        const int m  = ovf_list[ch >> 4];
        const int n0 = (ch & 15) << 6;
#pragma unroll 4
        for (int ii = 0; ii < 16; ++ii) {
            const int n = n0 + (wv << 4) + ii;
            const float p = wave_dot(X, C, m, n, l);
            if (l == 0) {
                const float d2 = (x_sq[m] - 2.0f * p) + c_sq[n];
                const u64 pk = ((u64)__float_as_uint(d2) << 32) | (u32)n;
                atomicMin(&packed_g[m], pk);
            }
        }
        __threadfence();                    // release: publish atomicMins
        __syncthreads();                    // all 4 waves' mins issued+fenced
        if (tid == 0) {
            const int old = atomicSub(&ovf_cnt[m], 1);
            __threadfence();                // acquire side for the winner
            s_flag = (old == 1);
        }
        __syncthreads();
        if (s_flag && tid < 64) {           // wave 0 gathers the final row
            __threadfence();
            const int bi = (int)(packed_g[m] & 1023u);
            gather_write(table, bias, out, m, bi, l);
        }
        __syncthreads();                    // protect s_flag for next chunk
    }
}

// ---------------------------------------------------------------------------
// Launch: 5 dispatches (gemm split in two for profiler visibility).
// Workspace map (byte offsets):
//   Xh       0           33,554,432
//   Ch       33,554,432   2,097,152
//   x_sq     35,651,584      65,536
//   c_sq     35,717,120       4,096
//   pt1      35,721,216   1,048,576  (u64 [8][16384])
//   pt2      36,769,792   1,048,576
//   pt3      37,818,368   1,048,576
//   packed_g 38,866,944     131,072  (u64 [16384])
//   ovf_list 38,998,016      65,536
//   ovf_cnt  39,063,552      65,536
//   g_ctr    39,129,088           8
// ---------------------------------------------------------------------------
extern "C" void kernel_launch(void* const* d_in, const int* in_sizes, int n_in,
                              void* d_out, int out_size, void* d_ws, size_t ws_size,
                              hipStream_t stream)
{
    const float* X     = (const float*)d_in[0];
    const float* C     = (const float*)d_in[1];
    const float* table = (const float*)d_in[2];
    const float* bias  = (const float*)d_in[3];
    float* out = (float*)d_out;

    char* ws = (char*)d_ws;
    u16*   Xh       = (u16*)(ws);
    u16*   Ch       = (u16*)(ws + 33554432);
    float* x_sq     = (float*)(ws + 35651584);
    float* c_sq     = (float*)(ws + 35717120);
    u64*   pt1      = (u64*)(ws + 35721216);
    u64*   pt2      = (u64*)(ws + 36769792);
    u64*   pt3      = (u64*)(ws + 37818368);
    u64*   packed_g = (u64*)(ws + 38866944);
    int*   ovf_list = (int*)(ws + 38998016);
    int*   ovf_cnt  = (int*)(ws + 39063552);
    int*   g_ctr    = (int*)(ws + 39129088);

    prep_kernel<<<(N_TOK + N_CENT) / 4, 256, 0, stream>>>(X, C, Xh, Ch,
                                                          x_sq, c_sq, g_ctr);

    dim3 hgrid(N_TOK / BM, NTILE / 2);   // 128 x 4, twice
    gemm_top3_kernel<<<hgrid, 256, 0, stream>>>(Xh, Ch, x_sq, c_sq,
                                                pt1, pt2, pt3, 0);
    gemm_top3_kernel<<<hgrid, 256, 0, stream>>>(Xh, Ch, x_sq, c_sq,
                                                pt1, pt2, pt3, 4);

    tail_kernel<<<TAIL_BLOCKS, 256, 0, stream>>>(pt1, pt2, pt3, X, C,
                                                 x_sq, c_sq, table, bias, out,
                                                 packed_g, ovf_list, ovf_cnt,
                                                 g_ctr);

    ovf_kernel<<<1024, 256, 0, stream>>>(X, C, x_sq, c_sq, ovf_list, g_ctr,
                                         packed_g, ovf_cnt, table, bias, out);
}

// Round 9
// 215.051 us; speedup vs baseline: 1.0627x; 1.0627x over previous
//
#include <hip/hip_runtime.h>

// Problem constants
#define N_TOK  16384   // B*S
#define D_IN   1024
#define D_OUT  1024
#define N_CENT 1024

// GEMM tiling (BK=32: R3 measured 59.9us vs 64.6 at BK=64)
#define BM 128
#define BN 128
#define BK 32
#define NTILE (N_CENT / BN)   // 8

// Fused tail: tokens per block. 512 blocks -> 2/CU.
#define TOK_PER_BLK 32
#define TAIL_BLOCKS (N_TOK / TOK_PER_BLK)   // 512

// Margin: bf16 approx error on d2 max ~1.6e-2 over all pairs; TAU >= 2*maxerr
// guarantees (a) unique-gap argmin exact, (b) candidate set {d2a <= gmin+TAU}
// contains the exact argmin. TAU=0.05 validated R3/R4/R5/R7/R8 (absmax 0).
#define TAU 0.05f

#define SENT 0xFFFFFFFFFFFFFFFFull

typedef __attribute__((ext_vector_type(8))) short short8;
typedef __attribute__((ext_vector_type(4))) float float4v;
typedef unsigned int u32;
typedef unsigned short u16;
typedef unsigned long long u64;

__device__ __forceinline__ void async_copy16(const void* g, void* l) {
    __builtin_amdgcn_global_load_lds(
        (const __attribute__((address_space(1))) u32*)g,
        (__attribute__((address_space(3))) u32*)l, 16, 0, 0);
}

__device__ __forceinline__ u16 f32_to_bf16_rne(float f) {
    u32 u = __float_as_uint(f);
    u32 r = (u + 0x7FFFu + ((u >> 16) & 1u)) >> 16;
    return (u16)r;
}

__device__ __forceinline__ u64 umin64(u64 a, u64 b) { return a < b ? a : b; }
__device__ __forceinline__ u64 umax64(u64 a, u64 b) { return a > b ? a : b; }
__device__ __forceinline__ float pk_val(u64 p) { return __uint_as_float((u32)(p >> 32)); }

// Merge two ascending-sorted u64 triples into (s1,s2,s3).
// Packed key (d2_bits<<32)|idx with d2>0: u64 order == lex (val, idx) ==
// numpy first-occurrence argmin tie-break. (R8-validated, absmax 0.)
__device__ __forceinline__ void merge3u(
    u64& s1, u64& s2, u64& s3, u64 b1, u64 b2, u64 b3)
{
    const u64 m1 = umin64(s1, b1);
    const u64 M1 = umax64(s1, b1);
    const u64 m2 = umin64(s2, b2);
    const u64 m3 = umin64(s3, b3);
    s1 = m1;
    const u64 t2 = umin64(M1, m2);
    s3 = umin64(umax64(M1, m2), m3);
    s2 = t2;
}

// Wave dot product, summation order identical to R5/R7/R8-validated rescore.
__device__ __forceinline__ float wave_dot(
    const float* __restrict__ X, const float* __restrict__ C,
    int m, int n, int l)
{
    const float4* xr = (const float4*)(X + (size_t)m * D_IN);
    const float4* cr = (const float4*)(C + (size_t)n * D_IN);
    float p = 0.f;
#pragma unroll
    for (int k = 0; k < 4; ++k) {
        const float4 cv = cr[l + 64 * k];
        const float4 xv = xr[l + 64 * k];
        p = fmaf(xv.x, cv.x, p); p = fmaf(xv.y, cv.y, p);
        p = fmaf(xv.z, cv.z, p); p = fmaf(xv.w, cv.w, p);
    }
#pragma unroll
    for (int off = 32; off > 0; off >>= 1) p += __shfl_xor(p, off);
    return p;
}

__device__ __forceinline__ void gather_write(
    const float* __restrict__ table, const float* __restrict__ bias,
    float* __restrict__ out, int m, int bi, int l)
{
    const float4* tr = (const float4*)(table + (size_t)bi * D_OUT);
    const float4* br = (const float4*)bias;
    float4* orow = (float4*)(out + (size_t)m * D_OUT);
#pragma unroll
    for (int i = 0; i < 4; ++i) {
        const float4 tv = tr[l + i * 64];
        const float4 bv = br[l + i * 64];
        orow[l + i * 64] = make_float4(tv.x + bv.x, tv.y + bv.y,
                                       tv.z + bv.z, tv.w + bv.w);
    }
}

// ---------------------------------------------------------------------------
// Fused fp32->bf16 convert + row norms for X and C + ovf counter zero.
// ---------------------------------------------------------------------------
__global__ __launch_bounds__(256) void prep_kernel(
    const float* __restrict__ X, const float* __restrict__ C,
    u16* __restrict__ Xh, u16* __restrict__ Ch,
    float* __restrict__ xsq, float* __restrict__ csq,
    int* __restrict__ g_ctr)
{
    if (blockIdx.x == 0 && threadIdx.x < 2) g_ctr[threadIdx.x] = 0;

    const int wv = threadIdx.x >> 6;
    const int l  = threadIdx.x & 63;
    int row = blockIdx.x * 4 + wv;
    const float* src; u16* dsth; float* dsts;
    if (row < N_TOK) { src = X; dsth = Xh; dsts = xsq; }
    else { row -= N_TOK; src = C; dsth = Ch; dsts = csq; }
    const float4* xr = (const float4*)(src + (size_t)row * D_IN);
    ushort4* hr = (ushort4*)(dsth + (size_t)row * D_IN);
    float s = 0.f;
#pragma unroll
    for (int i = 0; i < 4; ++i) {
        float4 v = xr[l + i * 64];
        ushort4 o;
        o.x = f32_to_bf16_rne(v.x); o.y = f32_to_bf16_rne(v.y);
        o.z = f32_to_bf16_rne(v.z); o.w = f32_to_bf16_rne(v.w);
        hr[l + i * 64] = o;
        s += v.x * v.x + v.y * v.y + v.z * v.z + v.w * v.w;
    }
#pragma unroll
    for (int off = 32; off > 0; off >>= 1) s += __shfl_down(s, off);
    if (l == 0) dsts[row] = s;
}

// ---------------------------------------------------------------------------
// bf16 MFMA GEMM + fused per-tile top-3 epilogue (u64-packed, R8-proven).
// R9: R4-exact structure (single buffer, __syncthreads, (r>>1)&3 swizzle,
// bank-conflict 0) + __launch_bounds__(256, 3). R8 occupancy arithmetic:
// 23.8% == exactly 2 blocks/CU; 76 arch-VGPR + ~64 AGPR + granularity
// lands the unified allocation just over the 170-reg 3-wave/SIMD line.
// min-waves=3 caps the allocator at 170 -> 3 blocks/CU -> a SECOND overlap
// partner for every vmcnt(0)+barrier drain (m114 implicit overlap is the
// only latency-hiding that works in this 2-phase structure: R6 dbuf null,
// R7 counted-vmcnt -70%).
// ---------------------------------------------------------------------------
__global__ __launch_bounds__(256, 3) void gemm_top3_kernel(
    const u16* __restrict__ Xh, const u16* __restrict__ Ch,
    const float* __restrict__ x_sq, const float* __restrict__ c_sq,
    u64* __restrict__ pt1, u64* __restrict__ pt2, u64* __restrict__ pt3)
{
    __shared__ __align__(16) u16 As[BM * BK];   // 8 KB
    __shared__ __align__(16) u16 Bs[BN * BK];   // 8 KB

    const int t  = threadIdx.x;
    const int w  = t >> 6;
    const int l  = t & 63;
    const int wi = w >> 1, wj = w & 1;
    const int m0 = blockIdx.x * BM;
    const int n0 = blockIdx.y * BN;
    const int quad = l >> 4;
    const int r15  = l & 15;

    float4v acc[4][4];
#pragma unroll
    for (int i = 0; i < 4; ++i)
#pragma unroll
        for (int j = 0; j < 4; ++j)
            acc[i][j] = (float4v){0.f, 0.f, 0.f, 0.f};

    for (int k0 = 0; k0 < D_IN; k0 += BK) {
        // 512 16B slots per operand: slot s -> row r=s>>2, lds-octet s&3,
        // global octet (s&3)^((r>>1)&3).  (R4 conflict-free swizzle)
#pragma unroll
        for (int rnd = 0; rnd < 2; ++rnd) {
            const int s = rnd * 256 + t;
            const int r = s >> 2;
            const int q = (s & 3) ^ ((r >> 1) & 3);
            async_copy16(Xh + (size_t)(m0 + r) * D_IN + k0 + q * 8, As + s * 8);
            async_copy16(Ch + (size_t)(n0 + r) * D_IN + k0 + q * 8, Bs + s * 8);
        }
        __syncthreads();

        short8 af[4], bfr[4];
#pragma unroll
        for (int i = 0; i < 4; ++i) {
            const int r = wi * 64 + i * 16 + r15;
            af[i] = *(const short8*)(As + (r * 4 + (quad ^ ((r >> 1) & 3))) * 8);
        }
#pragma unroll
        for (int j = 0; j < 4; ++j) {
            const int r = wj * 64 + j * 16 + r15;
            bfr[j] = *(const short8*)(Bs + (r * 4 + (quad ^ ((r >> 1) & 3))) * 8);
        }
#pragma unroll
        for (int i = 0; i < 4; ++i)
#pragma unroll
            for (int j = 0; j < 4; ++j)
                acc[i][j] = __builtin_amdgcn_mfma_f32_16x16x32_bf16(
                    af[i], bfr[j], acc[i][j], 0, 0, 0);
        __syncthreads();
    }

    // Epilogue: per-64-col-subtile top-3 (u64-packed), cross-wave merge.
    u64* red = (u64*)As;   // [BM][2] triples = 6144 B, reuses staging arena

    const int nbase = n0 + wj * 64 + r15;
    float cq[4];
#pragma unroll
    for (int j = 0; j < 4; ++j) cq[j] = c_sq[nbase + j * 16];

#pragma unroll
    for (int i = 0; i < 4; ++i) {
#pragma unroll
        for (int reg = 0; reg < 4; ++reg) {
            const int rloc = wi * 64 + i * 16 + quad * 4 + reg;
            const float xq = x_sq[m0 + rloc];
            const float d0 = (xq - 2.0f * acc[i][0][reg]) + cq[0];
            u64 s1 = ((u64)__float_as_uint(d0) << 32) | (u32)nbase;
            u64 s2 = SENT, s3 = SENT;
#pragma unroll
            for (int j = 1; j < 4; ++j) {
                const float dj = (xq - 2.0f * acc[i][j][reg]) + cq[j];
                const u64 v = ((u64)__float_as_uint(dj) << 32) | (u32)(nbase + j * 16);
                if (v < s1)      { s3 = s2; s2 = s1; s1 = v; }
                else if (v < s2) { s3 = s2; s2 = v; }
                else if (v < s3) { s3 = v; }
            }
#pragma unroll
            for (int off = 1; off < 16; off <<= 1) {
                const u64 b1 = __shfl_xor(s1, off);
                const u64 b2 = __shfl_xor(s2, off);
                const u64 b3 = __shfl_xor(s3, off);
                merge3u(s1, s2, s3, b1, b2, b3);
            }
            if (r15 == 0) {
                red[(rloc * 2 + wj) * 3 + 0] = s1;
                red[(rloc * 2 + wj) * 3 + 1] = s2;
                red[(rloc * 2 + wj) * 3 + 2] = s3;
            }
        }
    }
    __syncthreads();
    if (t < BM) {
        u64 a1 = red[(t * 2) * 3], a2 = red[(t * 2) * 3 + 1], a3 = red[(t * 2) * 3 + 2];
        merge3u(a1, a2, a3,
                red[(t * 2 + 1) * 3], red[(t * 2 + 1) * 3 + 1], red[(t * 2 + 1) * 3 + 2]);
        const size_t o = (size_t)blockIdx.y * N_TOK + m0 + t;
        pt1[o] = a1; pt2[o] = a2; pt3[o] = a3;
    }
}

// ---------------------------------------------------------------------------
// Fused tail for the COMMON path: reduce + candidate rescore + gather, all
// block-local (R8 numerics). R9: phase-1 pt loads parallelized across all
// 256 threads (8 threads/token x 3 loads via LDS; was 32 threads x 24
// serial loads with 224 threads idle). Merge order & numerics identical.
// Rare ovf tokens deferred to the globally-parallel ovf kernel.
// ---------------------------------------------------------------------------
__global__ __launch_bounds__(256) void tail_kernel(
    const u64* __restrict__ pt1, const u64* __restrict__ pt2,
    const u64* __restrict__ pt3,
    const float* __restrict__ X, const float* __restrict__ C,
    const float* __restrict__ x_sq, const float* __restrict__ c_sq,
    const float* __restrict__ table, const float* __restrict__ bias,
    float* __restrict__ out,
    u64* __restrict__ packed_g, int* __restrict__ ovf_list,
    int* __restrict__ ovf_cnt, int* __restrict__ g_ctr)
{
    __shared__ u64 s_t[TOK_PER_BLK][NTILE][3];       // 6 KB staged triples
    __shared__ u32 s_work[TOK_PER_BLK * 2 * NTILE];  // 2KB, exact worst case
    __shared__ u64 s_packed[TOK_PER_BLK];
    __shared__ int s_idx[TOK_PER_BLK];
    __shared__ int s_skip[TOK_PER_BLK];
    __shared__ int s_nw;

    const int tid = threadIdx.x;
    const int m0  = blockIdx.x * TOK_PER_BLK;
    const int wv  = tid >> 6;
    const int l   = tid & 63;

    if (tid == 0) s_nw = 0;

    // ---- Phase 1a: cooperative triple load (8 threads per token) ----
    {
        const int tok = tid >> 3;            // 0..31
        const int q   = tid & 7;             // 0..7
        const int m   = m0 + tok;
        s_t[tok][q][0] = pt1[(size_t)q * N_TOK + m];
        s_t[tok][q][1] = pt2[(size_t)q * N_TOK + m];
        s_t[tok][q][2] = pt3[(size_t)q * N_TOK + m];
    }
    __syncthreads();

    // ---- Phase 1b: per-token merge of NTILE triples (R8 logic, from LDS) ----
    if (tid < TOK_PER_BLK) {
        const int m = m0 + tid;
        u64 g1 = s_t[tid][0][0], g2 = s_t[tid][0][1], g3 = s_t[tid][0][2];
#pragma unroll
        for (int q = 1; q < NTILE; ++q)
            merge3u(g1, g2, g3, s_t[tid][q][0], s_t[tid][q][1], s_t[tid][q][2]);

        const float thr = pk_val(g1) + TAU;
        s_idx[tid] = (int)(g1 & 1023u);
        s_packed[tid] = SENT;

        bool ovf = false;
#pragma unroll
        for (int q = 0; q < NTILE; ++q)
            if (pk_val(s_t[tid][q][2]) <= thr) ovf = true;

        s_skip[tid] = ovf ? 1 : 0;
        if (ovf) {
            // Defer: full-row exact rescore with GLOBAL parallelism.
            packed_g[m] = SENT;                       // init before append
            ovf_cnt[m]  = 16;                         // 16 chunks pending
            const int pos = atomicAdd(&g_ctr[0], 1);  // device-scope
            ovf_list[pos] = m;
        } else if (pk_val(g2) <= thr) {
            int k = 0; u32 cd[2 * NTILE];
#pragma unroll
            for (int q = 0; q < NTILE; ++q) {
                if (pk_val(s_t[tid][q][0]) <= thr) cd[k++] = (u32)(s_t[tid][q][0] & 1023u);
                if (pk_val(s_t[tid][q][1]) <= thr) cd[k++] = (u32)(s_t[tid][q][1] & 1023u);
            }
            const int base = atomicAdd(&s_nw, k);
            for (int i = 0; i < k; ++i)
                s_work[base + i] = ((u32)tid << 10) | cd[i];
        }
    }
    __syncthreads();

    // ---- Phase 2: exact fp32 candidate rescore (bounded: <=16/token) ----
    {
        const int nw = s_nw;
        for (int i = wv; i < nw; i += 4) {
            const u32 item = s_work[i];
            const int mt = (int)(item >> 10);
            const int n  = (int)(item & 1023u);
            const int m = m0 + mt;
            const float p = wave_dot(X, C, m, n, l);
            if (l == 0) {
                const float d2 = (x_sq[m] - 2.0f * p) + c_sq[n];
                const u64 pk = ((u64)__float_as_uint(d2) << 32) | (u32)n;
                atomicMin(&s_packed[mt], pk);
            }
        }
    }
    __syncthreads();

    // ---- Phase 3: gather + bias for non-deferred tokens ----
    for (int mt = wv; mt < TOK_PER_BLK; mt += 4) {
        if (s_skip[mt]) continue;
        const u64 pk = s_packed[mt];
        const int bi = (pk != SENT) ? (int)(pk & 1023u) : s_idx[mt];
        gather_write(table, bias, out, m0 + mt, bi, l);
    }
}

// ---------------------------------------------------------------------------
// Deferred ovf rescore + fused gather. Chunks of 64 centroids spread over
// the grid (16 chunks/token); exact fp32 wave_dot + global u64 atomicMin
// (R8 numerics). Last-decrementer of the token's chunk counter gathers.
// ---------------------------------------------------------------------------
__global__ __launch_bounds__(256) void ovf_kernel(
    const float* __restrict__ X, const float* __restrict__ C,
    const float* __restrict__ x_sq, const float* __restrict__ c_sq,
    const int* __restrict__ ovf_list, const int* __restrict__ g_ctr,
    u64* __restrict__ packed_g, int* __restrict__ ovf_cnt,
    const float* __restrict__ table, const float* __restrict__ bias,
    float* __restrict__ out)
{
    __shared__ int s_flag;
    const int tid = threadIdx.x;
    const int wv = tid >> 6;
    const int l  = tid & 63;
    const int novf = g_ctr[0];
    const int nchunks = novf << 4;          // 16 x 64-centroid chunks per token
    for (int ch = blockIdx.x; ch < nchunks; ch += gridDim.x) {
        const int m  = ovf_list[ch >> 4];
        const int n0 = (ch & 15) << 6;
#pragma unroll 4
        for (int ii = 0; ii < 16; ++ii) {
            const int n = n0 + (wv << 4) + ii;
            const float p = wave_dot(X, C, m, n, l);
            if (l == 0) {
                const float d2 = (x_sq[m] - 2.0f * p) + c_sq[n];
                const u64 pk = ((u64)__float_as_uint(d2) << 32) | (u32)n;
                atomicMin(&packed_g[m], pk);
            }
        }
        __threadfence();                    // release: publish atomicMins
        __syncthreads();                    // all 4 waves' mins issued+fenced
        if (tid == 0) {
            const int old = atomicSub(&ovf_cnt[m], 1);
            __threadfence();                // acquire side for the winner
            s_flag = (old == 1);
        }
        __syncthreads();
        if (s_flag && tid < 64) {           // wave 0 gathers the final row
            __threadfence();
            const int bi = (int)(packed_g[m] & 1023u);
            gather_write(table, bias, out, m, bi, l);
        }
        __syncthreads();                    // protect s_flag for next chunk
    }
}

// ---------------------------------------------------------------------------
// Launch: 4 dispatches. Workspace map (byte offsets):
//   Xh       0           33,554,432
//   Ch       33,554,432   2,097,152
//   x_sq     35,651,584      65,536
//   c_sq     35,717,120       4,096
//   pt1      35,721,216   1,048,576  (u64 [8][16384])
//   pt2      36,769,792   1,048,576
//   pt3      37,818,368   1,048,576
//   packed_g 38,866,944     131,072  (u64 [16384])
//   ovf_list 38,998,016      65,536
//   ovf_cnt  39,063,552      65,536
//   g_ctr    39,129,088           8
// ---------------------------------------------------------------------------
extern "C" void kernel_launch(void* const* d_in, const int* in_sizes, int n_in,
                              void* d_out, int out_size, void* d_ws, size_t ws_size,
                              hipStream_t stream)
{
    const float* X     = (const float*)d_in[0];
    const float* C     = (const float*)d_in[1];
    const float* table = (const float*)d_in[2];
    const float* bias  = (const float*)d_in[3];
    float* out = (float*)d_out;

    char* ws = (char*)d_ws;
    u16*   Xh       = (u16*)(ws);
    u16*   Ch       = (u16*)(ws + 33554432);
    float* x_sq     = (float*)(ws + 35651584);
    float* c_sq     = (float*)(ws + 35717120);
    u64*   pt1      = (u64*)(ws + 35721216);
    u64*   pt2      = (u64*)(ws + 36769792);
    u64*   pt3      = (u64*)(ws + 37818368);
    u64*   packed_g = (u64*)(ws + 38866944);
    int*   ovf_list = (int*)(ws + 38998016);
    int*   ovf_cnt  = (int*)(ws + 39063552);
    int*   g_ctr    = (int*)(ws + 39129088);

    prep_kernel<<<(N_TOK + N_CENT) / 4, 256, 0, stream>>>(X, C, Xh, Ch,
                                                          x_sq, c_sq, g_ctr);

    dim3 grid(N_TOK / BM, N_CENT / BN);   // 128 x 8
    gemm_top3_kernel<<<grid, 256, 0, stream>>>(Xh, Ch, x_sq, c_sq,
                                               pt1, pt2, pt3);

    tail_kernel<<<TAIL_BLOCKS, 256, 0, stream>>>(pt1, pt2, pt3, X, C,
                                                 x_sq, c_sq, table, bias, out,
                                                 packed_g, ovf_list, ovf_cnt,
                                                 g_ctr);

    ovf_kernel<<<1024, 256, 0, stream>>>(X, C, x_sq, c_sq, ovf_list, g_ctr,
                                         packed_g, ovf_cnt, table, bias, out);
}